// Round 1
// baseline (346.310 us; speedup 1.0000x reference)
//
#include <hip/hip_runtime.h>

// LUT layout in d_ws (float): scale s entry a -> 8 floats [pb0,pb1,pb2,v0..v4]
// bases (floats): s0=0, s1=64, s2=576, s3=4672; total 37440 floats = 149,760 B.

__global__ __launch_bounds__(256) void build_lut_kernel(
    const float* __restrict__ pat,   // (4,3,4096)
    const float* __restrict__ pos,   // (4,5,4096)
    const int*   __restrict__ conn,  // (4,5,12)
    float* __restrict__ lut)
{
    int t = blockIdx.x * 256 + threadIdx.x;
    if (t >= 4680) return;
    int s, a, basef;
    if (t < 8)        { s = 0; a = t;       basef = 0; }
    else if (t < 72)  { s = 1; a = t - 8;   basef = 64; }
    else if (t < 584) { s = 2; a = t - 72;  basef = 576; }
    else              { s = 3; a = t - 584; basef = 4672; }
    int n = s + 1;
    int tn = 3 * n;           // ctx bits
    int in_bits = tn + 3;     // ctx + pbits
    int nb = in_bits < 12 ? in_bits : 12;

    // pos_in bit j (j<tn) is paddr bit (tn-1-j); paddr == a
    unsigned posmask = 0;
    for (int j = 0; j < tn; ++j)
        posmask |= (((unsigned)a >> (tn - 1 - j)) & 1u) << j;

    float outv[8];
    for (int j = 0; j < 3; ++j) {
        float v = pat[(s * 3 + j) * 4096 + a];
        unsigned b = (v > 0.5f) ? 1u : 0u;
        outv[j] = (float)b;
        posmask |= b << (tn + j);
    }
    for (int k = 0; k < 5; ++k) {
        unsigned addr = 0;
        for (int j = 0; j < nb; ++j) {
            int c = conn[(s * 5 + k) * 12 + j] % in_bits;
            addr |= ((posmask >> c) & 1u) << j;
        }
        outv[3 + k] = pos[(s * 5 + k) * 4096 + addr];
    }
    float4* d4 = (float4*)(lut + basef + a * 8);
    d4[0] = make_float4(outv[0], outv[1], outv[2], outv[3]);
    d4[1] = make_float4(outv[4], outv[5], outv[6], outv[7]);
}

__global__ __launch_bounds__(256) void gather_kernel(
    const int* __restrict__ type_bits,   // (B,12) in {0,1}
    const float* __restrict__ lut,
    float4* __restrict__ out4,           // B*8 float4s
    int nsamp, long long total4)
{
    __shared__ unsigned pshare[256];
    int t = threadIdx.x;
    long long sample = (long long)blockIdx.x * 256 + t;

    // Pack 12 bits: tb[0] -> bit 11 ... tb[11] -> bit 0.
    unsigned P = 0;
    if (sample < nsamp) {
        const int4* tb4 = (const int4*)type_bits + sample * 3;  // 48B/sample, 16B aligned
        int4 x = tb4[0], y = tb4[1], z = tb4[2];
        P = ((unsigned)x.x << 11) | ((unsigned)x.y << 10) | ((unsigned)x.z << 9) | ((unsigned)x.w << 8)
          | ((unsigned)y.x << 7)  | ((unsigned)y.y << 6)  | ((unsigned)y.z << 5) | ((unsigned)y.w << 4)
          | ((unsigned)z.x << 3)  | ((unsigned)z.y << 2)  | ((unsigned)z.z << 1) |  (unsigned)z.w;
    }
    pshare[t] = P;
    __syncthreads();

    // Thread t writes output float4s with within-sample chunk = t&7 (loop-invariant).
    // chunk = 2*s + half; LUT entry = 8 floats = 2 float4s.
    int s    = (t & 7) >> 1;
    int half = t & 1;
    unsigned mask  = (8u << (3 * s)) - 1u;                                  // 2^{3n}-1
    unsigned base4 = (unsigned)((0x0490009000100000ull >> (16 * s)) & 0xFFFFull); // {0,16,144,1168}
    const float4* lutp = (const float4*)lut + base4 + half;

    long long outBase = (long long)blockIdx.x * 2048 + t;
    int srow = t >> 3;
#pragma unroll
    for (int i = 0; i < 8; ++i) {
        long long g = outBase + (long long)(i * 256);
        if (g < total4) {
            unsigned Ps = pshare[i * 32 + srow];   // broadcast among 8 lanes, conflict-free
            out4[g] = lutp[(Ps & mask) * 2];
        }
    }
}

extern "C" void kernel_launch(void* const* d_in, const int* in_sizes, int n_in,
                              void* d_out, int out_size, void* d_ws, size_t ws_size,
                              hipStream_t stream) {
    const int*   type_bits = (const int*)d_in[0];
    const float* pat       = (const float*)d_in[1];
    const float* pos       = (const float*)d_in[2];
    const int*   conn      = (const int*)d_in[3];
    float* lut = (float*)d_ws;   // needs 149,760 B

    int nsamp = in_sizes[0] / 12;                 // 2,000,000
    long long total4 = (long long)out_size / 4;   // 16,000,000 float4s

    build_lut_kernel<<<(4680 + 255) / 256, 256, 0, stream>>>(pat, pos, conn, lut);
    int nblocks = (nsamp + 255) / 256;
    gather_kernel<<<nblocks, 256, 0, stream>>>(type_bits, lut, (float4*)d_out, nsamp, total4);
}